// Round 1
// baseline (184.762 us; speedup 1.0000x reference)
//
#include <hip/hip_runtime.h>
#include <math.h>

#define NG 201      // full grid size (k2/k3)
#define NI 101      // exploited symmetry: i = 100 + ii, ii in [0,100]
#define CI 32       // ii-chunk
#define BLOCK 256
#define LOG2_10 3.3219280948873623f
#define PI_F 3.14159265358979f

__global__ __launch_bounds__(BLOCK, 2)
void spectral_kernel(const float* __restrict__ k1_in,
                     const float* __restrict__ dy_in,
                     const float* __restrict__ dz_in,
                     const float* __restrict__ plogL,
                     const float* __restrict__ plogT,
                     const float* __restrict__ plogM,
                     float* __restrict__ out)
{
    __shared__ __attribute__((aligned(16))) float s_B3[NG * 64];   // cos(grid[j]*dz[z]) [j][z]
    __shared__ __attribute__((aligned(16))) float s_phi[NG * CI];  // Pw chunk [j][ii_local]; reused as T[32][64]
    __shared__ float s_grid[NG + 3];
    __shared__ float s_w[NG + 3];
    __shared__ float s_dy[64];
    __shared__ float s_dz[64];
    __shared__ float s_red[8];

    const int t = threadIdx.x;
    const int a = blockIdx.x;

    const float L  = expf(plogL[0]);
    const float Tt = expf(plogT[0]);
    const float M  = expf(plogM[0]);
    const float L2 = L * L;
    const float k1 = k1_in[a];

    // ---- grid: logspace(-2,2,100)^2, mirrored with 0 in the middle ----
    if (t < NG) {
        float v;
        if (t < 100)       v = -exp2f(LOG2_10 * (-4.0f + 8.0f * (float)(99 - t) * (1.0f/99.0f)));
        else if (t == 100) v = 0.0f;
        else               v =  exp2f(LOG2_10 * (-4.0f + 8.0f * (float)(t - 101) * (1.0f/99.0f)));
        s_grid[t] = v;
    }
    if (t < 64) { s_dy[t] = dy_in[t]; s_dz[t] = dz_in[t]; }
    __syncthreads();
    // ---- trapz weights ----
    if (t < NG) {
        float wv;
        if (t == 0)         wv = 0.5f * (s_grid[1] - s_grid[0]);
        else if (t == NG-1) wv = 0.5f * (s_grid[NG-1] - s_grid[NG-2]);
        else                wv = 0.5f * (s_grid[t+1] - s_grid[t-1]);
        s_w[t] = wv;
    }
    __syncthreads();
    // ---- B3 cos table ----
    for (int idx = t; idx < NG * 64; idx += BLOCK) {
        int j = idx >> 6, z = idx & 63;
        s_B3[idx] = cosf(s_grid[j] * s_dz[z]);
    }
    __syncthreads();

    float f1 = 0.0f;
    float oacc[16];
    #pragma unroll
    for (int k = 0; k < 16; ++k) oacc[k] = 0.0f;

    const int zs   = t & 63;        // stage1: z column; stage2/out: y row
    const int grp  = t >> 6;        // wave id 0..3
    const int iig0 = grp * 8;       // stage1: 8 ii rows per wave
    const int z0   = grp * 16;      // stage2: 16 z per thread
    const float dyv = s_dy[zs];

    for (int cb = 0; cb < NI; cb += CI) {
        const int rows = min(CI, NI - cb);

        // ---- phase A: Pw chunk (with weights + symmetry multiplier folded in) ----
        for (int idx = t; idx < NG * CI; idx += BLOCK) {
            const int j  = idx >> 5;
            const int il = idx & (CI - 1);
            float pw = 0.0f;
            if (il < rows) {
                const int ii = cb + il;
                const float k2 = s_grid[100 + ii];
                const float k3 = s_grid[j];
                const float kk  = k1*k1 + k2*k2 + k3*k3;
                const float beta = Tt * exp2f((-1.0f/3.0f) * log2f(L2 * kk));
                const float k30 = k3 + beta * k1;
                const float kk0 = k1*k1 + k2*k2 + k30*k30;
                const float u   = L2 * kk0;                       // (L*sqrt(kk0))^2
                const float E0  = M * u * u * exp2f((-17.0f/6.0f) * log2f(1.0f + u));
                const float s   = k1*k1 + k2*k2;
                const float C1  = beta*k1*k1*(kk0 - 2.0f*k30*k30 + beta*k1*k30) / (kk * s);
                const float sqs = sqrtf(s);
                const float C2  = k2 * kk0 / (s * sqs) * atan2f(beta*k1*sqs, kk0 - k30*k1*beta);
                const float zeta1 = C1 - (k2 / k1) * C2;
                const float qq  = kk0 - k1*k1 - 2.0f*k1*k30*zeta1 + s*zeta1*zeta1;
                const float phi = E0 * qq / (4.0f * PI_F * kk0 * kk0);
                const float mult = (ii == 0) ? 1.0f : 2.0f;       // symmetry fold (i and 200-i)
                pw = mult * phi * s_w[100 + ii] * s_w[j];
                f1 += pw;
            }
            s_phi[idx] = pw;
        }
        __syncthreads();

        // ---- stage 1: Tc[ii][z] = sum_j Pw[ii][j] * cos(k3[j]*dz[z]) ----
        float acc[8];
        #pragma unroll
        for (int r = 0; r < 8; ++r) acc[r] = 0.0f;
        if (iig0 < rows) {                       // wave-uniform skip on ragged last chunk
            #pragma unroll 3
            for (int j = 0; j < NG; ++j) {
                const float b = s_B3[j * 64 + zs];
                const float4* p4 = reinterpret_cast<const float4*>(&s_phi[j * CI + iig0]);
                const float4 pa = p4[0], pb = p4[1];   // wave-uniform broadcast
                acc[0] += pa.x * b; acc[1] += pa.y * b; acc[2] += pa.z * b; acc[3] += pa.w * b;
                acc[4] += pb.x * b; acc[5] += pb.y * b; acc[6] += pb.z * b; acc[7] += pb.w * b;
            }
        }
        __syncthreads();
        float* s_T = s_phi;                      // reuse (8KB <= 25.7KB)
        if (iig0 < rows) {
            #pragma unroll
            for (int r = 0; r < 8; ++r) s_T[(iig0 + r) * 64 + zs] = acc[r];
        }
        __syncthreads();

        // ---- stage 2: out[y][z] += cos(k2[ii]*dy[y]) * Tc[ii][z] ----
        for (int il = 0; il < rows; ++il) {
            const float cy = cosf(s_grid[100 + cb + il] * dyv);
            const float4* t4 = reinterpret_cast<const float4*>(&s_T[il * 64 + z0]);
            const float4 t0 = t4[0], t1 = t4[1], t2 = t4[2], t3 = t4[3];
            oacc[0]  += cy * t0.x; oacc[1]  += cy * t0.y; oacc[2]  += cy * t0.z; oacc[3]  += cy * t0.w;
            oacc[4]  += cy * t1.x; oacc[5]  += cy * t1.y; oacc[6]  += cy * t1.z; oacc[7]  += cy * t1.w;
            oacc[8]  += cy * t2.x; oacc[9]  += cy * t2.y; oacc[10] += cy * t2.z; oacc[11] += cy * t2.w;
            oacc[12] += cy * t3.x; oacc[13] += cy * t3.y; oacc[14] += cy * t3.z; oacc[15] += cy * t3.w;
        }
        __syncthreads();
    }

    // ---- F1 block reduction -> 1/|F1| ----
    float v = f1;
    #pragma unroll
    for (int off = 32; off > 0; off >>= 1) v += __shfl_down(v, off, 64);
    if ((t & 63) == 0) s_red[t >> 6] = v;
    __syncthreads();
    if (t == 0) s_red[4] = 1.0f / fabsf(s_red[0] + s_red[1] + s_red[2] + s_red[3]);
    __syncthreads();
    const float rden = s_red[4];

    // ---- write out[a][y][z], y=zs, z=z0..z0+15 ----
    float* op = out + ((size_t)a << 12) + (size_t)(zs * 64 + z0);
    #pragma unroll
    for (int k = 0; k < 16; k += 4) {
        float4 o;
        o.x = oacc[k+0] * rden; o.y = oacc[k+1] * rden;
        o.z = oacc[k+2] * rden; o.w = oacc[k+3] * rden;
        reinterpret_cast<float4*>(op + k)[0] = o;
    }
}

extern "C" void kernel_launch(void* const* d_in, const int* in_sizes, int n_in,
                              void* d_out, int out_size, void* d_ws, size_t ws_size,
                              hipStream_t stream) {
    const float* k1 = (const float*)d_in[0];
    const float* dy = (const float*)d_in[1];
    const float* dz = (const float*)d_in[2];
    const float* lL = (const float*)d_in[3];
    const float* lT = (const float*)d_in[4];
    const float* lM = (const float*)d_in[5];
    float* outp = (float*)d_out;
    hipLaunchKernelGGL(spectral_kernel, dim3(512), dim3(BLOCK), 0, stream,
                       k1, dy, dz, lL, lT, lM, outp);
}

// Round 3
// 96.350 us; speedup vs baseline: 1.9176x; 1.9176x over previous
//
#include <hip/hip_runtime.h>
#include <math.h>

#define BLOCK 256
#define LOG2_10 3.3219280948873623f
#define PI_F 3.14159265358979f
#define INV2PI 0.15915494309189535f
#define PW_SCALE 256.0f   // lifts Pw out of f16-subnormal range; cancels in out = num/F1

// LDS row strides in f16 elements
#define SP 224   // phiT / B3T: Kpad=224 (7 MFMA K-steps), 28 granules, 4-way XOR swizzle
#define SA 128   // A2: 16 granules, 8-way XOR swizzle
#define ST 64    // TcT: 8 granules, 8-way XOR swizzle

typedef _Float16 half8 __attribute__((ext_vector_type(8)));
typedef _Float16 half4 __attribute__((ext_vector_type(4)));
typedef _Float16 half2v __attribute__((ext_vector_type(2)));
typedef float f32x4 __attribute__((ext_vector_type(4)));

__device__ __forceinline__ float fast_cos(float x_rev) {
    // cos(2*pi*x_rev); v_fract + v_cos keeps the HW instruction in-domain
    return __builtin_amdgcn_cosf(__builtin_amdgcn_fractf(x_rev));
}

__device__ __forceinline__ float atan2_pos(float y, float x) {
    // assumes y >= 0; returns atan2(y,x) in [0, pi]
    float ax = __builtin_fabsf(x);
    float mn = fminf(ax, y), mx = fmaxf(ax, y);
    float a = mn * __builtin_amdgcn_rcpf(mx);
    float t = a * a;
    float p = fmaf(fmaf(fmaf(fmaf(fmaf(-0.0117212f, t, 0.05265332f), t,
              -0.11643287f), t, 0.19354346f), t, -0.33262347f), t, 0.99997726f);
    p *= a;
    p = (y > ax) ? (1.57079632679f - p) : p;
    p = (x < 0.0f) ? (3.14159265359f - p) : p;
    return p;
}

__global__ __launch_bounds__(BLOCK, 2)
void spectral_kernel(const float* __restrict__ k1_in,
                     const float* __restrict__ dy_in,
                     const float* __restrict__ dz_in,
                     const float* __restrict__ plogL,
                     const float* __restrict__ plogT,
                     const float* __restrict__ plogM,
                     float* __restrict__ out)
{
    __shared__ __attribute__((aligned(16))) _Float16 s_phiT[32 * SP]; // A1: [ii][j]
    __shared__ __attribute__((aligned(16))) _Float16 s_B3T[64 * SP];  // B1: [z][j]
    __shared__ __attribute__((aligned(16))) _Float16 s_A2[64 * SA];   // A2: [y][ii]
    __shared__ __attribute__((aligned(16))) _Float16 s_TcT[64 * ST];  // B2: [z][ii-local]
    __shared__ float  s_grid[204];
    __shared__ float2 s_gw[204];     // {grid[j], trapz_w[j]} (w=0 for j>200)
    __shared__ float  s_dy[64], s_dz[64];
    __shared__ float  s_red[8];

    const int t    = threadIdx.x;
    const int a    = blockIdx.x;
    const int lane = t & 63;
    const int w    = t >> 6;       // wave id 0..3
    const int n16  = lane & 15;
    const int quad = lane >> 4;

    const float L  = expf(plogL[0]);
    const float Tt = expf(plogT[0]);
    const float M  = expf(plogM[0]);
    const float L2 = L * L;
    const float k1   = k1_in[a];
    const float k1sq = k1 * k1;
    const float rk1  = __builtin_amdgcn_rcpf(k1);

    // ---- grid (extend 201..203 with grid[200]; safe finite pads) ----
    if (t < 204) {
        int tt = min(t, 200);
        float v;
        if (tt < 100)       v = -exp2f(LOG2_10 * (-4.0f + 8.0f * (float)(99 - tt) * (1.0f/99.0f)));
        else if (tt == 100) v = 0.0f;
        else                v =  exp2f(LOG2_10 * (-4.0f + 8.0f * (float)(tt - 101) * (1.0f/99.0f)));
        s_grid[t] = v;
    }
    if (t < 64) { s_dy[t] = dy_in[t]; s_dz[t] = dz_in[t]; }
    __syncthreads();

    // ---- trapz weights packed with grid ----
    if (t < 204) {
        float wv = 0.0f;
        if (t == 0)          wv = 0.5f * (s_grid[1] - s_grid[0]);
        else if (t < 200)    wv = 0.5f * (s_grid[t+1] - s_grid[t-1]);
        else if (t == 200)   wv = 0.5f * (s_grid[200] - s_grid[199]);
        s_gw[t] = make_float2(s_grid[t], wv);
    }
    // ---- B3T[z][j] = cos(grid[j]*dz[z]) as f16, zero-padded j>200 ----
    {
        float dzr = s_dz[lane] * INV2PI;
        for (int k = 0; k < 28; ++k) {
            int jp = w + 4 * k;                 // pair index 0..111
            int j0 = 2 * jp, j1 = j0 + 1;
            float c0 = (j0 <= 200) ? fast_cos(s_grid[j0] * dzr) : 0.0f;
            float c1 = (j1 <= 200) ? fast_cos(s_grid[j1] * dzr) : 0.0f;
            half2v pr; pr.x = (_Float16)c0; pr.y = (_Float16)c1;
            int off = lane * SP + (((jp >> 2) ^ (lane & 3)) << 3) + ((jp & 3) << 1);
            *(half2v*)&s_B3T[off] = pr;
        }
    }
    // ---- A2[y][ii] = cos(grid2[ii]*dy[y]) as f16, zero-padded ii>100 ----
    {
        float dyr = s_dy[lane] * INV2PI;
        for (int k = 0; k < 16; ++k) {
            int iip = w + 4 * k;                // pair index 0..63
            int i0 = 2 * iip, i1 = i0 + 1;
            float c0 = (i0 <= 100) ? fast_cos(s_grid[100 + i0] * dyr) : 0.0f;
            float c1 = (i1 <= 100) ? fast_cos(s_grid[100 + i1] * dyr) : 0.0f;
            half2v pr; pr.x = (_Float16)c0; pr.y = (_Float16)c1;
            int off = lane * SA + (((iip >> 2) ^ (lane & 7)) << 3) + ((iip & 3) << 1);
            *(half2v*)&s_A2[off] = pr;
        }
    }
    __syncthreads();

    float f1 = 0.0f;
    f32x4 acc2[4];
    #pragma unroll
    for (int i = 0; i < 4; ++i) acc2[i] = (f32x4){0.f, 0.f, 0.f, 0.f};

    const int il  = t & 31;       // phase-A ii-local (fixed per thread)
    const int jpb = t >> 5;       // phase-A pair base 0..7

    for (int c = 0; c < 4; ++c) {
        const int cb = c * 32;
        const int ii = cb + il;
        const bool act = (ii <= 100);

        // per-ii hoists
        float k2 = act ? s_grid[100 + ii] : 0.0f;
        float w2m = act ? (s_gw[100 + ii].y * ((ii == 0) ? 1.0f : 2.0f)) : 0.0f;
        const float cM = (M * 0.25f / PI_F) * PW_SCALE * w2m;  // M/(4pi)*scale*w2*mult
        const float s  = k1sq + k2 * k2;
        const float rs = __builtin_amdgcn_rsqf(s);
        const float sqs = s * rs;
        const float s15inv = rs * rs * rs;
        const float k2ok1  = k2 * rk1;

        // ---- phase A: pw = Phi11*w2*w3*mult*scale, fp32 -> f16 into phiT[ii][j] ----
        for (int k = 0; k < 14; ++k) {
            int jp = jpb + (k << 3);            // 0..111
            float pw0 = 0.0f, pw1 = 0.0f;
            if (act && jp <= 100) {
                float2 gw0 = s_gw[2 * jp];
                float2 gw1 = s_gw[2 * jp + 1];
                #pragma unroll
                for (int e = 0; e < 2; ++e) {
                    float k3 = e ? gw1.x : gw0.x;
                    float w3 = e ? gw1.y : gw0.y;
                    float kk   = fmaf(k3, k3, s);
                    float beta = Tt * __builtin_amdgcn_exp2f((-1.0f/3.0f) * __builtin_amdgcn_logf(L2 * kk));
                    float bk1  = beta * k1;
                    float k30  = k3 + bk1;
                    float kk0  = fmaf(k30, k30, s);
                    float u    = L2 * kk0;
                    float e0   = u * u * __builtin_amdgcn_exp2f((-17.0f/6.0f) * __builtin_amdgcn_logf(1.0f + u));
                    float C1   = bk1 * k1 * (kk0 - 2.0f * k30 * k30 + bk1 * k30)
                                 * __builtin_amdgcn_rcpf(kk * s);
                    float th   = atan2_pos(bk1 * sqs, kk0 - k30 * bk1);
                    float C2   = k2 * kk0 * s15inv * th;
                    float zeta = C1 - k2ok1 * C2;
                    float rk   = __builtin_amdgcn_rcpf(kk0);
                    float qq   = fmaf(fmaf(s, zeta, -2.0f * k1 * k30), zeta, kk0 - k1sq);
                    float pw   = cM * e0 * qq * rk * rk * w3;
                    if (e) pw1 = pw; else pw0 = pw;
                }
                f1 += pw0 + pw1;
            }
            half2v pr; pr.x = (_Float16)pw0; pr.y = (_Float16)pw1;
            *(half2v*)&s_phiT[il * SP + (((jp >> 2) ^ (il & 3)) << 3) + ((jp & 3) << 1)] = pr;
        }
        __syncthreads();   // B1: phiT ready

        // ---- stage 1 (MFMA): TcT[z][ii] = sum_j phiT[ii][j]*B3T[z][j] ----
        {
            const int mt  = w & 1;
            const int nt0 = (w >> 1) << 1;
            f32x4 acc1a = {0.f,0.f,0.f,0.f}, acc1b = {0.f,0.f,0.f,0.f};
            const int arow  = mt * 16 + n16;
            const int brow0 = nt0 * 16 + n16;
            const int brow1 = brow0 + 16;
            #pragma unroll
            for (int ks = 0; ks < 7; ++ks) {
                int kg = ks * 4 + quad;
                half8 af  = *(const half8*)&s_phiT[arow  * SP + ((kg ^ (arow  & 3)) << 3)];
                half8 bf0 = *(const half8*)&s_B3T [brow0 * SP + ((kg ^ (brow0 & 3)) << 3)];
                half8 bf1 = *(const half8*)&s_B3T [brow1 * SP + ((kg ^ (brow1 & 3)) << 3)];
                acc1a = __builtin_amdgcn_mfma_f32_16x16x32_f16(af, bf0, acc1a, 0, 0, 0);
                acc1b = __builtin_amdgcn_mfma_f32_16x16x32_f16(af, bf1, acc1b, 0, 0, 0);
            }
            // C-layout: col=lane&15 (z), row=quad*4+r (ii-local). Pack 4 f16 -> b64.
            const int ii0 = mt * 16 + quad * 4;
            const int g   = ii0 >> 3;
            const int wi  = ii0 & 7;
            {
                int z = brow0;
                half4 hv; hv.x=(_Float16)acc1a.x; hv.y=(_Float16)acc1a.y;
                hv.z=(_Float16)acc1a.z; hv.w=(_Float16)acc1a.w;
                *(half4*)&s_TcT[z * ST + ((g ^ (z & 7)) << 3) + wi] = hv;
            }
            {
                int z = brow1;
                half4 hv; hv.x=(_Float16)acc1b.x; hv.y=(_Float16)acc1b.y;
                hv.z=(_Float16)acc1b.z; hv.w=(_Float16)acc1b.w;
                *(half4*)&s_TcT[z * ST + ((g ^ (z & 7)) << 3) + wi] = hv;
            }
        }
        __syncthreads();   // B2: TcT ready

        // ---- stage 2 (MFMA): out[y][z] += A2[y][ii]*TcT[z][ii], K=32/chunk ----
        {
            const int yrow = w * 16 + n16;
            const int G = c * 4 + quad;
            half8 a2f = *(const half8*)&s_A2[yrow * SA + ((G ^ (yrow & 7)) << 3)];
            #pragma unroll
            for (int nt = 0; nt < 4; ++nt) {
                int z = nt * 16 + n16;
                half8 bf = *(const half8*)&s_TcT[z * ST + ((quad ^ (z & 7)) << 3)];
                acc2[nt] = __builtin_amdgcn_mfma_f32_16x16x32_f16(a2f, bf, acc2[nt], 0, 0, 0);
            }
        }
        __syncthreads();   // TcT/phiT reused next chunk
    }

    // ---- F1 block reduction -> 1/|F1| (scaled; cancels PW_SCALE) ----
    float v = f1;
    #pragma unroll
    for (int off = 32; off > 0; off >>= 1) v += __shfl_down(v, off, 64);
    if (lane == 0) s_red[w] = v;
    __syncthreads();
    if (t == 0) s_red[4] = 1.0f / fabsf(s_red[0] + s_red[1] + s_red[2] + s_red[3]);
    __syncthreads();
    const float rden = s_red[4];

    // ---- epilogue: D2 C-layout -> out[a][y][z] ----
    float* op = out + ((size_t)a << 12);
    #pragma unroll
    for (int nt = 0; nt < 4; ++nt) {
        int z = nt * 16 + n16;
        #pragma unroll
        for (int r = 0; r < 4; ++r) {
            int y = w * 16 + quad * 4 + r;
            op[y * 64 + z] = acc2[nt][r] * rden;
        }
    }
}

extern "C" void kernel_launch(void* const* d_in, const int* in_sizes, int n_in,
                              void* d_out, int out_size, void* d_ws, size_t ws_size,
                              hipStream_t stream) {
    const float* k1 = (const float*)d_in[0];
    const float* dy = (const float*)d_in[1];
    const float* dz = (const float*)d_in[2];
    const float* lL = (const float*)d_in[3];
    const float* lT = (const float*)d_in[4];
    const float* lM = (const float*)d_in[5];
    float* outp = (float*)d_out;
    hipLaunchKernelGGL(spectral_kernel, dim3(512), dim3(BLOCK), 0, stream,
                       k1, dy, dz, lL, lT, lM, outp);
}

// Round 4
// 88.616 us; speedup vs baseline: 2.0850x; 1.0873x over previous
//
#include <hip/hip_runtime.h>
#include <math.h>

#define BLOCK 256
#define LOG2_10 3.3219280948873623f
#define PI_F 3.14159265358979f
#define INV2PI 0.15915494309189535f
#define PW_SCALE 256.0f   // lifts Pw out of f16-subnormal range; cancels in out = num/F1

// LDS row strides in f16 elements
#define SP 128   // phiT / B3T: j folded 201->101, Kpad=128 (4 MFMA K-steps), 16 granules, XOR row&7
#define SA 128   // A2: 16 granules, XOR row&7
#define ST 64    // TcT: 8 granules, XOR row&7

typedef _Float16 half8 __attribute__((ext_vector_type(8)));
typedef _Float16 half4 __attribute__((ext_vector_type(4)));
typedef _Float16 half2v __attribute__((ext_vector_type(2)));
typedef float f32x4 __attribute__((ext_vector_type(4)));

__device__ __forceinline__ float fast_cos(float x_rev) {
    return __builtin_amdgcn_cosf(__builtin_amdgcn_fractf(x_rev));
}

__device__ __forceinline__ float atan2_pos(float y, float x) {
    // assumes y >= 0; returns atan2(y,x) in [0, pi]
    float ax = __builtin_fabsf(x);
    float mn = fminf(ax, y), mx = fmaxf(ax, y);
    float a = mn * __builtin_amdgcn_rcpf(mx);
    float t = a * a;
    float p = fmaf(fmaf(fmaf(fmaf(fmaf(-0.0117212f, t, 0.05265332f), t,
              -0.11643287f), t, 0.19354346f), t, -0.33262347f), t, 0.99997726f);
    p *= a;
    p = (y > ax) ? (1.57079632679f - p) : p;
    p = (x < 0.0f) ? (3.14159265359f - p) : p;
    return p;
}

__global__ __launch_bounds__(BLOCK, 2)
void spectral_kernel(const float* __restrict__ k1_in,
                     const float* __restrict__ dy_in,
                     const float* __restrict__ dz_in,
                     const float* __restrict__ plogL,
                     const float* __restrict__ plogT,
                     const float* __restrict__ plogM,
                     float* __restrict__ out)
{
    __shared__ __attribute__((aligned(16))) _Float16 s_phiT[32 * SP]; // A1: [ii][jj] (j-folded pair sums)
    __shared__ __attribute__((aligned(16))) _Float16 s_B3T[64 * SP];  // B1: [z][jj] cos table (j-sym)
    __shared__ __attribute__((aligned(16))) _Float16 s_A2[64 * SA];   // A2: [y][ii]
    __shared__ __attribute__((aligned(16))) _Float16 s_TcT[64 * ST];  // B2: [z][ii-local]
    __shared__ float  s_grid[204];
    __shared__ float2 s_gw[204];     // {grid[j], trapz_w[j]}
    __shared__ float  s_dy[64], s_dz[64];
    __shared__ float  s_red[8];

    const int t    = threadIdx.x;
    const int a    = blockIdx.x;
    const int lane = t & 63;
    const int w    = t >> 6;       // wave id 0..3
    const int n16  = lane & 15;
    const int quad = lane >> 4;

    const float L  = expf(plogL[0]);
    const float Tt = expf(plogT[0]);
    const float M  = expf(plogM[0]);
    const float L2 = L * L;
    const float k1   = k1_in[a];
    const float k1sq = k1 * k1;
    const float rk1  = __builtin_amdgcn_rcpf(k1);
    const float cM0  = (M * 0.25f / PI_F) * PW_SCALE;

    // ---- grid ----
    if (t < 204) {
        int tt = min(t, 200);
        float v;
        if (tt < 100)       v = -exp2f(LOG2_10 * (-4.0f + 8.0f * (float)(99 - tt) * (1.0f/99.0f)));
        else if (tt == 100) v = 0.0f;
        else                v =  exp2f(LOG2_10 * (-4.0f + 8.0f * (float)(tt - 101) * (1.0f/99.0f)));
        s_grid[t] = v;
    }
    if (t < 64) { s_dy[t] = dy_in[t]; s_dz[t] = dz_in[t]; }
    __syncthreads();

    // ---- trapz weights packed with grid ----
    if (t < 204) {
        float wv = 0.0f;
        if (t == 0)          wv = 0.5f * (s_grid[1] - s_grid[0]);
        else if (t < 200)    wv = 0.5f * (s_grid[t+1] - s_grid[t-1]);
        else if (t == 200)   wv = 0.5f * (s_grid[200] - s_grid[199]);
        s_gw[t] = make_float2(s_grid[t], wv);
    }
    // ---- B3T[z][jj] = cos(grid[100+jj]*dz[z]) f16 (j-symmetric), zero-pad jj>100 ----
    {
        const int jjp = lane;            // half2 pair index: jj = 2*jjp, 2*jjp+1
        const int jj0 = 2 * jjp, jj1 = jj0 + 1;
        const float g0 = s_grid[min(100 + jj0, 203)];
        const float g1 = s_grid[min(100 + jj1, 203)];
        const int jjg  = jjp >> 2;
        for (int m = 0; m < 16; ++m) {
            int z = w + 4 * m;
            float dzr = s_dz[z] * INV2PI;
            float c0 = (jj0 <= 100) ? fast_cos(g0 * dzr) : 0.0f;
            float c1 = (jj1 <= 100) ? fast_cos(g1 * dzr) : 0.0f;
            half2v pr; pr.x = (_Float16)c0; pr.y = (_Float16)c1;
            *(half2v*)&s_B3T[z * SP + ((jjg ^ (z & 7)) << 3) + (jj0 & 7)] = pr;
        }
    }
    // ---- A2[y][ii] = cos(grid2[ii]*dy[y]) f16, zero-pad ii>100 ----
    {
        float dyr = s_dy[lane] * INV2PI;
        for (int k = 0; k < 16; ++k) {
            int iip = w + 4 * k;                // pair index 0..63
            int i0 = 2 * iip, i1 = i0 + 1;
            float c0 = (i0 <= 100) ? fast_cos(s_grid[min(100 + i0, 203)] * dyr) : 0.0f;
            float c1 = (i1 <= 100) ? fast_cos(s_grid[min(100 + i1, 203)] * dyr) : 0.0f;
            half2v pr; pr.x = (_Float16)c0; pr.y = (_Float16)c1;
            int off = lane * SA + (((iip >> 2) ^ (lane & 7)) << 3) + ((iip & 3) << 1);
            *(half2v*)&s_A2[off] = pr;
        }
    }
    // ---- zero phiT once (covers pad granules jj=104..127 for all chunks) ----
    {
        half8 zz = {};
        *(half8*)&s_phiT[t * 8] = zz;
        *(half8*)&s_phiT[(t + 256) * 8] = zz;
    }
    __syncthreads();

    float f1 = 0.0f;
    f32x4 acc2[4];
    #pragma unroll
    for (int i = 0; i < 4; ++i) acc2[i] = (f32x4){0.f, 0.f, 0.f, 0.f};

    const int il = t >> 3;        // phase-A ii-local row 0..31
    const int jb = t & 7;         // phase-A jj sub-index

    for (int c = 0; c < 4; ++c) {
        if (c < 3) {
            // ---- phase A (structured): mirror-pair eval, pw(j0)+pw(j1) -> phiT[il][jj] ----
            const int ii = c * 32 + il;
            const float k2  = s_gw[100 + ii].x;
            const float w2m = s_gw[100 + ii].y * ((ii == 0) ? 1.0f : 2.0f);
            const float cM  = cM0 * w2m;
            const float s   = k1sq + k2 * k2;
            const float rs  = __builtin_amdgcn_rsqf(s);
            const float sqs = s * rs;
            const float s15inv = rs * rs * rs;
            const float k2ok1  = k2 * rk1;

            #pragma unroll 2
            for (int k = 0; k < 13; ++k) {
                const int jj = jb + (k << 3);          // 0..103
                const bool act = (jj <= 100);
                const float2 gwv = s_gw[100 + (act ? jj : 0)];
                const float g = gwv.x, w3 = gwv.y;
                // shared between mirror pair (k3 = -g and +g)
                const float kk   = fmaf(g, g, s);
                const float beta = Tt * __builtin_amdgcn_exp2f((-1.0f/3.0f) * __builtin_amdgcn_logf(L2 * kk));
                const float bk1  = beta * k1;
                const float rkks = __builtin_amdgcn_rcpf(kk * s);
                const float bkk1 = bk1 * k1;
                // side a: k3 = -g ; side b: k3 = +g
                float k30a = bk1 - g,        k30b = bk1 + g;
                float k3sa = k30a * k30a,    k3sb = k30b * k30b;
                float kk0a = s + k3sa,       kk0b = s + k3sb;
                float ua   = L2 * kk0a,      ub   = L2 * kk0b;
                float e0a  = ua * ua * __builtin_amdgcn_exp2f((-17.0f/6.0f) * __builtin_amdgcn_logf(1.0f + ua));
                float e0b  = ub * ub * __builtin_amdgcn_exp2f((-17.0f/6.0f) * __builtin_amdgcn_logf(1.0f + ub));
                float C1a  = bkk1 * (s - k3sa + bk1 * k30a) * rkks;
                float C1b  = bkk1 * (s - k3sb + bk1 * k30b) * rkks;
                float tha  = atan2_pos(bk1 * sqs, kk0a - k30a * bk1);
                float thb  = atan2_pos(bk1 * sqs, kk0b - k30b * bk1);
                float za   = C1a - k2ok1 * (k2 * kk0a * s15inv * tha);
                float zb   = C1b - k2ok1 * (k2 * kk0b * s15inv * thb);
                float rka  = __builtin_amdgcn_rcpf(kk0a);
                float rkb  = __builtin_amdgcn_rcpf(kk0b);
                float qqa  = fmaf(fmaf(s, za, -2.0f * k1 * k30a), za, kk0a - k1sq);
                float qqb  = fmaf(fmaf(s, zb, -2.0f * k1 * k30b), zb, kk0b - k1sq);
                float pws  = fmaf(e0a * qqa, rka * rka, e0b * qqb * rkb * rkb);
                float scale = (jj == 0) ? 0.5f : 1.0f;   // center j=100 counted once
                float val = act ? (pws * cM * w3 * scale) : 0.0f;
                f1 += val;
                s_phiT[il * SP + (((jj >> 3) ^ (il & 7)) << 3) + (jj & 7)] = (_Float16)val;
            }
        } else {
            // ---- chunk 3: rows ii=96..100 only. Zero rows 5..31, flatten 5x101 cells ----
            for (int idx = t; idx < 432; idx += 256) {
                half8 zz = {};
                *(half8*)&s_phiT[5 * SP + idx * 8] = zz;
            }
            #pragma unroll
            for (int m = 0; m < 2; ++m) {
                const int widx = t + 256 * m;
                if (widx < 505) {
                    const int il3 = widx / 101;
                    const int jj  = widx - il3 * 101;
                    const int ii  = 96 + il3;
                    const float k2  = s_gw[100 + ii].x;
                    const float cM  = cM0 * (s_gw[100 + ii].y * 2.0f);
                    const float s   = k1sq + k2 * k2;
                    const float rs  = __builtin_amdgcn_rsqf(s);
                    const float sqs = s * rs;
                    const float s15inv = rs * rs * rs;
                    const float k2ok1  = k2 * rk1;
                    const float2 gwv = s_gw[100 + jj];
                    const float g = gwv.x, w3 = gwv.y;
                    const float kk   = fmaf(g, g, s);
                    const float beta = Tt * __builtin_amdgcn_exp2f((-1.0f/3.0f) * __builtin_amdgcn_logf(L2 * kk));
                    const float bk1  = beta * k1;
                    const float rkks = __builtin_amdgcn_rcpf(kk * s);
                    const float bkk1 = bk1 * k1;
                    float k30a = bk1 - g,        k30b = bk1 + g;
                    float k3sa = k30a * k30a,    k3sb = k30b * k30b;
                    float kk0a = s + k3sa,       kk0b = s + k3sb;
                    float ua   = L2 * kk0a,      ub   = L2 * kk0b;
                    float e0a  = ua * ua * __builtin_amdgcn_exp2f((-17.0f/6.0f) * __builtin_amdgcn_logf(1.0f + ua));
                    float e0b  = ub * ub * __builtin_amdgcn_exp2f((-17.0f/6.0f) * __builtin_amdgcn_logf(1.0f + ub));
                    float C1a  = bkk1 * (s - k3sa + bk1 * k30a) * rkks;
                    float C1b  = bkk1 * (s - k3sb + bk1 * k30b) * rkks;
                    float tha  = atan2_pos(bk1 * sqs, kk0a - k30a * bk1);
                    float thb  = atan2_pos(bk1 * sqs, kk0b - k30b * bk1);
                    float za   = C1a - k2ok1 * (k2 * kk0a * s15inv * tha);
                    float zb   = C1b - k2ok1 * (k2 * kk0b * s15inv * thb);
                    float rka  = __builtin_amdgcn_rcpf(kk0a);
                    float rkb  = __builtin_amdgcn_rcpf(kk0b);
                    float qqa  = fmaf(fmaf(s, za, -2.0f * k1 * k30a), za, kk0a - k1sq);
                    float qqb  = fmaf(fmaf(s, zb, -2.0f * k1 * k30b), zb, kk0b - k1sq);
                    float pws  = fmaf(e0a * qqa, rka * rka, e0b * qqb * rkb * rkb);
                    float scale = (jj == 0) ? 0.5f : 1.0f;
                    float val = pws * cM * w3 * scale;
                    f1 += val;
                    s_phiT[il3 * SP + (((jj >> 3) ^ (il3 & 7)) << 3) + (jj & 7)] = (_Float16)val;
                }
            }
        }
        __syncthreads();   // B1: phiT ready

        // ---- stage 1 (MFMA): TcT[z][ii] = sum_jj phiT[ii][jj]*B3T[z][jj], K=128 ----
        {
            const int mt  = w & 1;
            const int nt0 = (w >> 1) << 1;
            f32x4 acc1a = {0.f,0.f,0.f,0.f}, acc1b = {0.f,0.f,0.f,0.f};
            const int arow  = mt * 16 + n16;
            const int brow0 = nt0 * 16 + n16;
            const int brow1 = brow0 + 16;
            #pragma unroll
            for (int ks = 0; ks < 4; ++ks) {
                int kg = ks * 4 + quad;
                half8 af  = *(const half8*)&s_phiT[arow  * SP + ((kg ^ (arow  & 7)) << 3)];
                half8 bf0 = *(const half8*)&s_B3T [brow0 * SP + ((kg ^ (brow0 & 7)) << 3)];
                half8 bf1 = *(const half8*)&s_B3T [brow1 * SP + ((kg ^ (brow1 & 7)) << 3)];
                acc1a = __builtin_amdgcn_mfma_f32_16x16x32_f16(af, bf0, acc1a, 0, 0, 0);
                acc1b = __builtin_amdgcn_mfma_f32_16x16x32_f16(af, bf1, acc1b, 0, 0, 0);
            }
            const int ii0 = mt * 16 + quad * 4;
            const int g   = ii0 >> 3;
            const int wi  = ii0 & 7;
            {
                int z = brow0;
                half4 hv; hv.x=(_Float16)acc1a.x; hv.y=(_Float16)acc1a.y;
                hv.z=(_Float16)acc1a.z; hv.w=(_Float16)acc1a.w;
                *(half4*)&s_TcT[z * ST + ((g ^ (z & 7)) << 3) + wi] = hv;
            }
            {
                int z = brow1;
                half4 hv; hv.x=(_Float16)acc1b.x; hv.y=(_Float16)acc1b.y;
                hv.z=(_Float16)acc1b.z; hv.w=(_Float16)acc1b.w;
                *(half4*)&s_TcT[z * ST + ((g ^ (z & 7)) << 3) + wi] = hv;
            }
        }
        __syncthreads();   // B2: TcT ready

        // ---- stage 2 (MFMA): out[y][z] += A2[y][ii]*TcT[z][ii], K=32/chunk ----
        {
            const int yrow = w * 16 + n16;
            const int G = c * 4 + quad;
            half8 a2f = *(const half8*)&s_A2[yrow * SA + ((G ^ (yrow & 7)) << 3)];
            #pragma unroll
            for (int nt = 0; nt < 4; ++nt) {
                int z = nt * 16 + n16;
                half8 bf = *(const half8*)&s_TcT[z * ST + ((quad ^ (z & 7)) << 3)];
                acc2[nt] = __builtin_amdgcn_mfma_f32_16x16x32_f16(a2f, bf, acc2[nt], 0, 0, 0);
            }
        }
        __syncthreads();   // phiT/TcT reused next chunk
    }

    // ---- F1 block reduction -> 1/|F1| (scaled; cancels PW_SCALE) ----
    float v = f1;
    #pragma unroll
    for (int off = 32; off > 0; off >>= 1) v += __shfl_down(v, off, 64);
    if (lane == 0) s_red[w] = v;
    __syncthreads();
    if (t == 0) s_red[4] = 1.0f / fabsf(s_red[0] + s_red[1] + s_red[2] + s_red[3]);
    __syncthreads();
    const float rden = s_red[4];

    // ---- epilogue: D2 C-layout -> out[a][y][z] ----
    float* op = out + ((size_t)a << 12);
    #pragma unroll
    for (int nt = 0; nt < 4; ++nt) {
        int z = nt * 16 + n16;
        #pragma unroll
        for (int r = 0; r < 4; ++r) {
            int y = w * 16 + quad * 4 + r;
            op[y * 64 + z] = acc2[nt][r] * rden;
        }
    }
}

extern "C" void kernel_launch(void* const* d_in, const int* in_sizes, int n_in,
                              void* d_out, int out_size, void* d_ws, size_t ws_size,
                              hipStream_t stream) {
    const float* k1 = (const float*)d_in[0];
    const float* dy = (const float*)d_in[1];
    const float* dz = (const float*)d_in[2];
    const float* lL = (const float*)d_in[3];
    const float* lT = (const float*)d_in[4];
    const float* lM = (const float*)d_in[5];
    float* outp = (float*)d_out;
    hipLaunchKernelGGL(spectral_kernel, dim3(512), dim3(BLOCK), 0, stream,
                       k1, dy, dz, lL, lT, lM, outp);
}

// Round 5
// 87.803 us; speedup vs baseline: 2.1043x; 1.0093x over previous
//
#include <hip/hip_runtime.h>
#include <math.h>

#define BLOCK 512
#define LOG2_10 3.3219280948873623f
#define PI_F 3.14159265358979f
#define INV2PI 0.15915494309189535f
#define PW_SCALE 256.0f   // lifts Pw out of f16-subnormal range; cancels in out = num/F1

// LDS row strides in f16 elements
#define SP 128   // phiT / B3T: j folded 201->101, Kpad=128 (4 MFMA K-steps), 16 granules, XOR row&7
#define SA 128   // A2: 16 granules, XOR row&7
#define ST 64    // TcT: 8 granules, XOR row&7

typedef _Float16 half8 __attribute__((ext_vector_type(8)));
typedef _Float16 half4 __attribute__((ext_vector_type(4)));
typedef _Float16 half2v __attribute__((ext_vector_type(2)));
typedef float f32x4 __attribute__((ext_vector_type(4)));

__device__ __forceinline__ float fast_cos(float x_rev) {
    return __builtin_amdgcn_cosf(__builtin_amdgcn_fractf(x_rev));
}

__device__ __forceinline__ float atan2_pos(float y, float x) {
    // assumes y >= 0; returns atan2(y,x) in [0, pi]
    float ax = __builtin_fabsf(x);
    float mn = fminf(ax, y), mx = fmaxf(ax, y);
    float a = mn * __builtin_amdgcn_rcpf(mx);
    float t = a * a;
    float p = fmaf(fmaf(fmaf(fmaf(fmaf(-0.0117212f, t, 0.05265332f), t,
              -0.11643287f), t, 0.19354346f), t, -0.33262347f), t, 0.99997726f);
    p *= a;
    p = (y > ax) ? (1.57079632679f - p) : p;
    p = (x < 0.0f) ? (3.14159265359f - p) : p;
    return p;
}

// mirror-pair Phi11 (k3 = -g, +g), with E0*rcp(kk0)^2 = L4*(1+u)^(-17/6) folded
// (L4 lives in the caller's cM constant). Returns the pair sum sans cM*w3.
__device__ __forceinline__ float phi_pair(float k1, float k1sq, float Tt, float L2,
                                          float s, float sqs, float s15inv,
                                          float k2, float k2ok1, float g) {
    const float kk   = fmaf(g, g, s);
    const float beta = Tt * __builtin_amdgcn_exp2f((-1.0f/3.0f) * __builtin_amdgcn_logf(L2 * kk));
    const float bk1  = beta * k1;
    const float rkks = __builtin_amdgcn_rcpf(kk * s);
    const float bkk1 = bk1 * k1;
    const float yv   = bk1 * sqs;
    float k30a = bk1 - g,      k30b = bk1 + g;
    float k3sa = k30a * k30a,  k3sb = k30b * k30b;
    float kk0a = s + k3sa,     kk0b = s + k3sb;
    float ua   = L2 * kk0a,    ub   = L2 * kk0b;
    float pa = __builtin_amdgcn_exp2f((-17.0f/6.0f) * __builtin_amdgcn_logf(1.0f + ua));
    float pb = __builtin_amdgcn_exp2f((-17.0f/6.0f) * __builtin_amdgcn_logf(1.0f + ub));
    float C1a = bkk1 * (s - k3sa + bk1 * k30a) * rkks;
    float C1b = bkk1 * (s - k3sb + bk1 * k30b) * rkks;
    float tha = atan2_pos(yv, kk0a - k30a * bk1);
    float thb = atan2_pos(yv, kk0b - k30b * bk1);
    float za  = C1a - k2ok1 * (k2 * kk0a * s15inv * tha);
    float zb  = C1b - k2ok1 * (k2 * kk0b * s15inv * thb);
    float qqa = fmaf(fmaf(s, za, -2.0f * k1 * k30a), za, kk0a - k1sq);
    float qqb = fmaf(fmaf(s, zb, -2.0f * k1 * k30b), zb, kk0b - k1sq);
    return fmaf(pa, qqa, pb * qqb);
}

__global__ __launch_bounds__(BLOCK, 4)
void spectral_kernel(const float* __restrict__ k1_in,
                     const float* __restrict__ dy_in,
                     const float* __restrict__ dz_in,
                     const float* __restrict__ plogL,
                     const float* __restrict__ plogT,
                     const float* __restrict__ plogM,
                     float* __restrict__ out)
{
    __shared__ __attribute__((aligned(16))) _Float16 s_phiT[32 * SP]; // A1: [ii][jj] pair sums
    __shared__ __attribute__((aligned(16))) _Float16 s_B3T[64 * SP];  // B1: [z][jj] cos (j-sym)
    __shared__ __attribute__((aligned(16))) _Float16 s_A2[64 * SA];   // A2: [y][ii]
    __shared__ __attribute__((aligned(16))) _Float16 s_TcT[64 * ST];  // B2: [z][ii-local]
    __shared__ float  s_grid[204];
    __shared__ float2 s_gw[204];     // {grid[j], trapz_w[j]}
    __shared__ float  s_dy[64], s_dz[64];
    __shared__ float  s_red[16];

    const int t    = threadIdx.x;
    const int a    = blockIdx.x;
    const int lane = t & 63;
    const int w    = t >> 6;       // wave id 0..7
    const int n16  = lane & 15;
    const int quad = lane >> 4;

    const float L  = expf(plogL[0]);
    const float Tt = expf(plogT[0]);
    const float M  = expf(plogM[0]);
    const float L2 = L * L;
    const float L4 = L2 * L2;
    const float k1   = k1_in[a];
    const float k1sq = k1 * k1;
    const float rk1  = __builtin_amdgcn_rcpf(k1);
    const float cM0  = (M * 0.25f / PI_F) * PW_SCALE * L4;

    // ---- grid ----
    if (t < 204) {
        int tt = min(t, 200);
        float v;
        if (tt < 100)       v = -exp2f(LOG2_10 * (-4.0f + 8.0f * (float)(99 - tt) * (1.0f/99.0f)));
        else if (tt == 100) v = 0.0f;
        else                v =  exp2f(LOG2_10 * (-4.0f + 8.0f * (float)(tt - 101) * (1.0f/99.0f)));
        s_grid[t] = v;
    }
    if (t < 64) { s_dy[t] = dy_in[t]; s_dz[t] = dz_in[t]; }
    __syncthreads();

    // ---- trapz weights packed with grid ----
    if (t < 204) {
        float wv = 0.0f;
        if (t == 0)          wv = 0.5f * (s_grid[1] - s_grid[0]);
        else if (t < 200)    wv = 0.5f * (s_grid[t+1] - s_grid[t-1]);
        else if (t == 200)   wv = 0.5f * (s_grid[200] - s_grid[199]);
        s_gw[t] = make_float2(s_grid[t], wv);
    }
    // ---- B3T[z][jj] = cos(grid[100+jj]*dz[z]) f16 (j-symmetric), zero-pad jj>100 ----
    {
        const int jjp = t & 63;          // half2 pair index: jj = 2*jjp, 2*jjp+1
        const int zg  = t >> 6;          // 0..7
        const int jj0 = 2 * jjp, jj1 = jj0 + 1;
        const float g0 = s_grid[min(100 + jj0, 203)];
        const float g1 = s_grid[min(100 + jj1, 203)];
        const int jjg  = jjp >> 2;
        #pragma unroll
        for (int m = 0; m < 8; ++m) {
            int z = zg + 8 * m;
            float dzr = s_dz[z] * INV2PI;
            float c0 = (jj0 <= 100) ? fast_cos(g0 * dzr) : 0.0f;
            float c1 = (jj1 <= 100) ? fast_cos(g1 * dzr) : 0.0f;
            half2v pr; pr.x = (_Float16)c0; pr.y = (_Float16)c1;
            *(half2v*)&s_B3T[z * SP + ((jjg ^ (z & 7)) << 3) + (jj0 & 7)] = pr;
        }
    }
    // ---- A2[y][ii] = cos(grid2[ii]*dy[y]) f16, zero-pad ii>100 ----
    {
        const int iip = t & 63;
        const int yg  = t >> 6;
        const int i0 = 2 * iip, i1 = i0 + 1;
        const float g0 = s_grid[min(100 + i0, 203)];
        const float g1 = s_grid[min(100 + i1, 203)];
        #pragma unroll
        for (int m = 0; m < 8; ++m) {
            int y = yg + 8 * m;
            float dyr = s_dy[y] * INV2PI;
            float c0 = (i0 <= 100) ? fast_cos(g0 * dyr) : 0.0f;
            float c1 = (i1 <= 100) ? fast_cos(g1 * dyr) : 0.0f;
            half2v pr; pr.x = (_Float16)c0; pr.y = (_Float16)c1;
            int off = y * SA + (((iip >> 2) ^ (y & 7)) << 3) + ((iip & 3) << 1);
            *(half2v*)&s_A2[off] = pr;
        }
    }
    // ---- zero phiT once (pad granules stay zero across chunks) ----
    {
        half8 zz = {};
        *(half8*)&s_phiT[t * 8] = zz;
    }
    __syncthreads();

    float f1 = 0.0f;
    f32x4 acc2[2];
    acc2[0] = (f32x4){0.f, 0.f, 0.f, 0.f};
    acc2[1] = (f32x4){0.f, 0.f, 0.f, 0.f};

    const int il = t >> 4;        // phase-A ii-local row 0..31
    const int jb = t & 15;        // phase-A jj sub-index

    for (int c = 0; c < 4; ++c) {
        if (c < 3) {
            // ---- phase A: mirror-pair eval -> phiT[il][jj] ----
            const int ii = c * 32 + il;
            const float k2  = s_gw[100 + ii].x;
            const float w2m = s_gw[100 + ii].y * ((ii == 0) ? 1.0f : 2.0f);
            const float cM  = cM0 * w2m;
            const float s   = k1sq + k2 * k2;
            const float rs  = __builtin_amdgcn_rsqf(s);
            const float sqs = s * rs;
            const float s15inv = rs * rs * rs;
            const float k2ok1  = k2 * rk1;

            #pragma unroll 2
            for (int k = 0; k < 7; ++k) {
                const int jj = jb + (k << 4);          // 0..111
                const bool act = (jj <= 100);
                const float2 gwv = s_gw[100 + (act ? jj : 0)];
                const float g = gwv.x, w3 = gwv.y;
                float pws = phi_pair(k1, k1sq, Tt, L2, s, sqs, s15inv, k2, k2ok1, g);
                float scale = (jj == 0) ? 0.5f : 1.0f;   // center j counted once
                float val = act ? (pws * cM * w3 * scale) : 0.0f;
                f1 += val;
                s_phiT[il * SP + (((jj >> 3) ^ (il & 7)) << 3) + (jj & 7)] = (_Float16)val;
            }
        } else {
            // ---- chunk 3: rows ii=96..100 only; zero rows 5..31, flatten 5x101 cells ----
            if (t < 432) {
                half8 zz = {};
                *(half8*)&s_phiT[5 * SP + t * 8] = zz;
            }
            if (t < 505) {
                const int il3 = t / 101;
                const int jj  = t - il3 * 101;
                const int ii  = 96 + il3;
                const float k2  = s_gw[100 + ii].x;
                const float cM  = cM0 * (s_gw[100 + ii].y * 2.0f);
                const float s   = k1sq + k2 * k2;
                const float rs  = __builtin_amdgcn_rsqf(s);
                const float sqs = s * rs;
                const float s15inv = rs * rs * rs;
                const float k2ok1  = k2 * rk1;
                const float2 gwv = s_gw[100 + jj];
                float pws = phi_pair(k1, k1sq, Tt, L2, s, sqs, s15inv, k2, k2ok1, gwv.x);
                float scale = (jj == 0) ? 0.5f : 1.0f;
                float val = pws * cM * gwv.y * scale;
                f1 += val;
                s_phiT[il3 * SP + (((jj >> 3) ^ (il3 & 7)) << 3) + (jj & 7)] = (_Float16)val;
            }
        }
        __syncthreads();   // B1: phiT ready

        // ---- stage 1 (MFMA): TcT[z][ii] = sum_jj phiT[ii][jj]*B3T[z][jj], K=128 ----
        {
            const int mt = w & 1;          // M-tile (ii 0..15 / 16..31)
            const int nt = w >> 1;         // N-tile (z block of 16)
            f32x4 acc1 = {0.f, 0.f, 0.f, 0.f};
            const int arow = mt * 16 + n16;
            const int brow = nt * 16 + n16;
            #pragma unroll
            for (int ks = 0; ks < 4; ++ks) {
                int kg = ks * 4 + quad;
                half8 af = *(const half8*)&s_phiT[arow * SP + ((kg ^ (arow & 7)) << 3)];
                half8 bf = *(const half8*)&s_B3T [brow * SP + ((kg ^ (brow & 7)) << 3)];
                acc1 = __builtin_amdgcn_mfma_f32_16x16x32_f16(af, bf, acc1, 0, 0, 0);
            }
            const int ii0 = mt * 16 + quad * 4;
            const int gg  = ii0 >> 3;
            const int wi  = ii0 & 7;
            half4 hv; hv.x=(_Float16)acc1.x; hv.y=(_Float16)acc1.y;
            hv.z=(_Float16)acc1.z; hv.w=(_Float16)acc1.w;
            *(half4*)&s_TcT[brow * ST + ((gg ^ (brow & 7)) << 3) + wi] = hv;
        }
        __syncthreads();   // B2: TcT ready

        // ---- stage 2 (MFMA): out[y][z] += A2[y][ii]*TcT[z][ii], K=32/chunk ----
        {
            const int yt  = w >> 1;
            const int zt0 = (w & 1) * 2;
            const int yrow = yt * 16 + n16;
            const int G = c * 4 + quad;
            half8 a2f = *(const half8*)&s_A2[yrow * SA + ((G ^ (yrow & 7)) << 3)];
            #pragma unroll
            for (int p = 0; p < 2; ++p) {
                int z = (zt0 + p) * 16 + n16;
                half8 bf = *(const half8*)&s_TcT[z * ST + ((quad ^ (z & 7)) << 3)];
                acc2[p] = __builtin_amdgcn_mfma_f32_16x16x32_f16(a2f, bf, acc2[p], 0, 0, 0);
            }
        }
        __syncthreads();   // phiT/TcT reused next chunk
    }

    // ---- F1 block reduction -> 1/|F1| ----
    float v = f1;
    #pragma unroll
    for (int off = 32; off > 0; off >>= 1) v += __shfl_down(v, off, 64);
    if (lane == 0) s_red[w] = v;
    __syncthreads();
    if (t == 0) {
        float sum = 0.0f;
        #pragma unroll
        for (int i = 0; i < 8; ++i) sum += s_red[i];
        s_red[8] = 1.0f / fabsf(sum);
    }
    __syncthreads();
    const float rden = s_red[8];

    // ---- epilogue: D2 C-layout -> out[a][y][z] ----
    float* op = out + ((size_t)a << 12);
    {
        const int yt  = w >> 1;
        const int zt0 = (w & 1) * 2;
        #pragma unroll
        for (int p = 0; p < 2; ++p) {
            int z = (zt0 + p) * 16 + n16;
            #pragma unroll
            for (int r = 0; r < 4; ++r) {
                int y = yt * 16 + quad * 4 + r;
                op[y * 64 + z] = acc2[p][r] * rden;
            }
        }
    }
}

extern "C" void kernel_launch(void* const* d_in, const int* in_sizes, int n_in,
                              void* d_out, int out_size, void* d_ws, size_t ws_size,
                              hipStream_t stream) {
    const float* k1 = (const float*)d_in[0];
    const float* dy = (const float*)d_in[1];
    const float* dz = (const float*)d_in[2];
    const float* lL = (const float*)d_in[3];
    const float* lT = (const float*)d_in[4];
    const float* lM = (const float*)d_in[5];
    float* outp = (float*)d_out;
    hipLaunchKernelGGL(spectral_kernel, dim3(512), dim3(BLOCK), 0, stream,
                       k1, dy, dz, lL, lT, lM, outp);
}